// Round 8
// baseline (145.635 us; speedup 1.0000x reference)
//
#include <hip/hip_runtime.h>

// Problem constants (fixed by the reference): B=16 lists, N=1024, D=256.
#define BL 16
#define NL 1024
#define DD 256

typedef short bf16x8 __attribute__((ext_vector_type(8)));
typedef float f32x4 __attribute__((ext_vector_type(4)));

static __device__ __forceinline__ short f32_to_bf16(float f) {
  union { float f; unsigned u; } v; v.f = f;
  unsigned r = (v.u + 0x7FFFu + ((v.u >> 16) & 1u)) >> 16;  // RNE
  return (short)r;
}

// Async 16B global -> LDS. LDS dest must be wave-uniform base + lane*16
// (m104/m108). Global source address IS per-lane -> pre-swizzled source.
static __device__ __forceinline__ void g2l16(const short* g, short* l) {
  __builtin_amdgcn_global_load_lds(
      (const __attribute__((address_space(1))) void*)g,
      (__attribute__((address_space(3))) void*)l, 16, 0, 0);
}

// ---- Kernel 1: prep. Blocks [0,4096): X fp32->bf16. [4096,4608): W transpose.
__global__ __launch_bounds__(256) void k_prep(const float* __restrict__ X,
                                              const float* __restrict__ Wu,
                                              const float* __restrict__ Wl,
                                              short* __restrict__ Xb,
                                              short* __restrict__ WTu,
                                              short* __restrict__ WTl) {
  const int bid = blockIdx.x;
  if (bid < 4096) {
    int i = bid * 256 + threadIdx.x;  // float4 groups over 16384*256 floats
    const float4 v = ((const float4*)X)[i];
    short4 o;
    o.x = f32_to_bf16(v.x); o.y = f32_to_bf16(v.y);
    o.z = f32_to_bf16(v.z); o.w = f32_to_bf16(v.w);
    ((short4*)Xb)[i] = o;
  } else {
    const int id = bid - 4096;           // [0,512)
    const int z = id >> 8, d = id & 255; // matrix, source row of W
    const float* W = z ? Wl : Wu;
    short* WT = z ? WTl : WTu;
    const int e = threadIdx.x;
    WT[e * DD + d] = f32_to_bf16(W[d * DD + e]);  // WT[e][d] = W[d][e]
  }
}

// ---- Kernel 2: fused stage1+stage2. Block = (list b, 64-row strip pt, q-half).
// Grid = 512 blocks x 512 thr (8 waves); LDS 64 KB (Yl aliased into the dead
// Asw buffer) -> 2 independent blocks/CU = 16 waves/CU in two scheduling
// streams (R7: ONE barrier-coupled block/CU -> diag tail + latency exposed,
// 27% occupancy). bid = z*16+b -> XCD = b%8: lists L2/L3-pinned as before.
// Phase 1 (dup x2 per strip, cheap): Y_U/Y_L[64x256] = Xp*W; wave w -> cols
// [w*32,+32), both matrices. Phase 2: wave w -> q-tile qh*8+w, 64x64 fat acc,
// 2-deep B-load pipeline pinned with sched_barrier(0) (R7: compiler sank the
// loads back to serial, VGPR stayed 64).
__global__ __launch_bounds__(512, 4) void k_fused(const short* __restrict__ Xb,
                                                  const short* __restrict__ WTu,
                                                  const short* __restrict__ WTl,
                                                  const float* __restrict__ bu_p,
                                                  const float* __restrict__ bl_p,
                                                  float* __restrict__ out) {
  __shared__ short Asw[64 * 256];  // phase1: swizzled Xp; phase2: swizzled Y_L
  __shared__ short Yu[64 * 256];   // swizzled Y_upper, 32 KB

  const int bid = blockIdx.x;
  const int b = bid & 15, z = bid >> 4;   // z in [0,32)
  const int pt = z >> 1, qh = z & 1;      // strip, q-half
  const int t = threadIdx.x, lane = t & 63, w = t >> 6;  // w in [0,8)
  const int r = lane & 15, quad = lane >> 4;
  const size_t listoff = (size_t)b * NL * DD;
  const short* Ap = Xb + listoff + (size_t)pt * 64 * DD;  // 64 x 256 bf16

  // ---- stage Xp into LDS, XOR-swizzled via pre-swizzled global source ----
  // 2048 16B-chunks (32/row); read at (row*512+kb)^((row&7)<<4) -> src c^((c>>5)&7)
#pragma unroll
  for (int i = 0; i < 4; ++i) {
    const int c = i * 512 + t;  // per wave: uniform base + lane*16
    const int src = c ^ ((c >> 5) & 7);
    g2l16(Ap + src * 8, Asw + c * 8);
  }
  __syncthreads();

  // ---- phase 1: Y = Xp * W for both matrices; wave w -> cols [w*32,+32) ----
  const int n0 = w * 32;
  f32x4 aU[4][2] = {}, aL[4][2] = {};
#pragma unroll
  for (int ks = 0; ks < 8; ++ks) {
    bf16x8 af[4];
#pragma unroll
    for (int mt = 0; mt < 4; ++mt) {
      const int row = mt * 16 + r;
      const int abyte = (row * 512 + ks * 64 + quad * 16) ^ ((row & 7) << 4);
      af[mt] = *(const bf16x8*)((const char*)Asw + abyte);
    }
    bf16x8 bfu[2], bfl[2];
#pragma unroll
    for (int nf = 0; nf < 2; ++nf) {
      const int off = (n0 + nf * 16 + r) * DD + ks * 32 + quad * 8;
      bfu[nf] = *(const bf16x8*)(WTu + off);
      bfl[nf] = *(const bf16x8*)(WTl + off);
    }
#pragma unroll
    for (int mt = 0; mt < 4; ++mt)
#pragma unroll
      for (int nf = 0; nf < 2; ++nf) {
        aU[mt][nf] = __builtin_amdgcn_mfma_f32_16x16x32_bf16(af[mt], bfu[nf], aU[mt][nf], 0, 0, 0);
        aL[mt][nf] = __builtin_amdgcn_mfma_f32_16x16x32_bf16(af[mt], bfl[nf], aL[mt][nf], 0, 0, 0);
      }
  }
  __syncthreads();  // all Asw reads done -> safe to overwrite with Y_L

  // write Y (bf16) into swizzled LDS: D[m][n]: row = mt*16+quad*4+i, col = n0+nf*16+r
#pragma unroll
  for (int mt = 0; mt < 4; ++mt)
#pragma unroll
    for (int nf = 0; nf < 2; ++nf)
#pragma unroll
      for (int i = 0; i < 4; ++i) {
        const int row = mt * 16 + quad * 4 + i;
        const int col = n0 + nf * 16 + r;
        const int byte = (row * 512 + col * 2) ^ ((row & 7) << 4);
        *(short*)((char*)Yu + byte) = f32_to_bf16(aU[mt][nf][i]);
        *(short*)((char*)Asw + byte) = f32_to_bf16(aL[mt][nf][i]);  // Y_L
      }

  // ---- phase 2 setup; B prefetch (global, no Y dep) issued pre-barrier ----
  const float ub = bu_p[0], lb = bl_p[0];
  float* Ob = out + (size_t)b * NL * NL;
  const int p0 = pt * 64;
  const int qt = qh * 8 + w, q0 = qt * 64;
  const short* Bg = Xb + listoff + (size_t)qt * 64 * DD;
  const float bias = (qt >= pt) ? ub : lb;

  auto loadB = [&](bf16x8 (&dst)[4], int ks) {
#pragma unroll
    for (int nt = 0; nt < 4; ++nt)
      dst[nt] = *(const bf16x8*)(Bg + (size_t)(nt * 16 + r) * DD + ks * 32 + quad * 8);
  };
  auto mmaStep = [&](const short* Y, const bf16x8 (&bf)[4], f32x4 (&ac)[4][4], int ks) {
#pragma unroll
    for (int mt = 0; mt < 4; ++mt) {
      const int row = mt * 16 + r;
      const int abyte = (row * 512 + ks * 64 + quad * 16) ^ ((row & 7) << 4);
      const bf16x8 af2 = *(const bf16x8*)((const char*)Y + abyte);
#pragma unroll
      for (int nt = 0; nt < 4; ++nt)
        ac[nt][mt] = __builtin_amdgcn_mfma_f32_16x16x32_bf16(bf[nt], af2, ac[nt][mt], 0, 0, 0);
    }
  };

  bf16x8 bfA[4], bfB[4];
  loadB(bfA, 0);   // in flight across the barrier
  loadB(bfB, 1);
  __builtin_amdgcn_sched_barrier(0);  // keep prefetch before the barrier
  __syncthreads();  // publish Yu / Y_L

  // ---- phase 2: barrier-free; wave w owns q-tile qt; pinned 2-deep pipe ----
  const short* YA = (qt >= pt) ? Yu : Asw;  // diag tile -> Upper in this pass
  f32x4 acc[4][4] = {};  // [nt][mt]: D rows <- q (B rows), cols <- p (Y rows)
  mmaStep(YA, bfA, acc, 0);  loadB(bfA, 2);  __builtin_amdgcn_sched_barrier(0);
  mmaStep(YA, bfB, acc, 1);  loadB(bfB, 3);  __builtin_amdgcn_sched_barrier(0);
  mmaStep(YA, bfA, acc, 2);  loadB(bfA, 4);  __builtin_amdgcn_sched_barrier(0);
  mmaStep(YA, bfB, acc, 3);  loadB(bfB, 5);  __builtin_amdgcn_sched_barrier(0);
  mmaStep(YA, bfA, acc, 4);  loadB(bfA, 6);  __builtin_amdgcn_sched_barrier(0);
  mmaStep(YA, bfB, acc, 5);  loadB(bfB, 7);  __builtin_amdgcn_sched_barrier(0);
  mmaStep(YA, bfA, acc, 6);
  mmaStep(YA, bfB, acc, 7);

  // stores: lane holds row p0+mt*16+r, 4 consecutive q per f32x4 (L2 merges)
#pragma unroll
  for (int mt = 0; mt < 4; ++mt) {
    float* row = Ob + (size_t)(p0 + mt * 16 + r) * NL;
#pragma unroll
    for (int nt = 0; nt < 4; ++nt) {
      f32x4 v;
#pragma unroll
      for (int i = 0; i < 4; ++i) v[i] = acc[nt][mt][i] + bias;
      *(f32x4*)(row + q0 + nt * 16 + quad * 4) = v;
    }
  }

  // ---- diag fixup: wave with qt==pt recomputes lower with Y_L, overwrites q<p ----
  if (qt == pt) {
    f32x4 accL[4][4] = {};
    loadB(bfA, 0);   // B tile just read -> L1/L2 hot
    loadB(bfB, 1);
    mmaStep(Asw, bfA, accL, 0);  loadB(bfA, 2);
    mmaStep(Asw, bfB, accL, 1);  loadB(bfB, 3);
    mmaStep(Asw, bfA, accL, 2);  loadB(bfA, 4);
    mmaStep(Asw, bfB, accL, 3);  loadB(bfB, 5);
    mmaStep(Asw, bfA, accL, 4);  loadB(bfA, 6);
    mmaStep(Asw, bfB, accL, 5);  loadB(bfB, 7);
    mmaStep(Asw, bfA, accL, 6);
    mmaStep(Asw, bfB, accL, 7);
#pragma unroll
    for (int mt = 0; mt < 4; ++mt) {
      const int p = p0 + mt * 16 + r;
      float* row = Ob + (size_t)p * NL;
#pragma unroll
      for (int nt = 0; nt < 4; ++nt)
#pragma unroll
        for (int i = 0; i < 4; ++i) {
          const int q = q0 + nt * 16 + quad * 4 + i;
          if (q < p) row[q] = accL[nt][mt][i] + lb;
        }
    }
  }
}

extern "C" void kernel_launch(void* const* d_in, const int* in_sizes, int n_in,
                              void* d_out, int out_size, void* d_ws, size_t ws_size,
                              hipStream_t stream) {
  const float* feats = (const float*)d_in[0];   // [B*N, D] fp32
  const float* Wu    = (const float*)d_in[1];   // [1, D, D]
  const float* bu    = (const float*)d_in[2];   // [1]
  const float* Wl    = (const float*)d_in[3];   // [1, D, D]
  const float* bl    = (const float*)d_in[4];   // [1]
  float* out = (float*)d_out;                   // [B, N, N] fp32

  char* ws = (char*)d_ws;
  short* Xb  = (short*)(ws);                                   // 8 MB bf16 X
  short* WTu = (short*)(ws + (size_t)8 * 1024 * 1024);         // 128 KB
  short* WTl = (short*)(ws + (size_t)8 * 1024 * 1024 + DD * DD * 2);

  // Prep: X->bf16 (4096 blocks) + W transpose (512 blocks), one dispatch.
  k_prep<<<4096 + 512, 256, 0, stream>>>(feats, Wu, Wl, Xb, WTu, WTl);

  // Fused stage1+stage2: 512 blocks (16 strips x 16 lists x 2 q-halves),
  // 512 threads, 64 KB LDS -> 2 blocks/CU. XCD = bid%8 = b%8.
  k_fused<<<512, 512, 0, stream>>>(Xb, WTu, WTl, bu, bl, out);
}